// Round 9
// baseline (879.808 us; speedup 1.0000x reference)
//
#include <hip/hip_runtime.h>
#include <stdint.h>

typedef __bf16 bf16x8 __attribute__((ext_vector_type(8)));
typedef float f32x16 __attribute__((ext_vector_type(16)));

#define NN 4096
#define FF 64
#define BM 32
#define BK 128
#define NSTEP (NN / BK)  // 32
#define NKB (NN / 16)    // 256 k16-blocks

// round-to-nearest-even fp32 -> bf16
__device__ __forceinline__ unsigned short f2bf(float x) {
    unsigned int u = __builtin_bit_cast(unsigned int, x);
    unsigned int r = u + 0x7fffu + ((u >> 16) & 1u);
    return (unsigned short)(r >> 16);
}

__device__ __forceinline__ void gload16(const void* g, void* l) {
    __builtin_amdgcn_global_load_lds((const __attribute__((address_space(1))) void*)g,
                                     (__attribute__((address_space(3))) void*)l, 16, 0, 0);
}

// Pass 1: annP[b][kb][f][kh] = bf16(ann[b][kb*16+kh][f])  — B fragment for k-block kb
// is 16 B/lane, 1 KB contiguous per wave. (Validated R4/R6: absmax 0.5.)
__global__ __launch_bounds__(256) void annP_kernel(const float* __restrict__ ann,
                                                   unsigned short* __restrict__ annP) {
    int blk = blockIdx.x;
    int b = blk >> 6;
    int kb = (blk & 63) * 4 + (threadIdx.x >> 6);
    int f = threadIdx.x & 63;
    const float* src = ann + (size_t)(b * NN + kb * 16) * FF + f;
    unsigned short v[16];
#pragma unroll
    for (int kh = 0; kh < 16; ++kh) v[kh] = f2bf(src[(size_t)kh * FF]);
    unsigned int p[8];
#pragma unroll
    for (int i = 0; i < 8; ++i) p[i] = (unsigned)v[2 * i] | ((unsigned)v[2 * i + 1] << 16);
    uint4* dst = (uint4*)(annP + ((size_t)(b * NKB + kb) * 64 + f) * 16);
    dst[0] = make_uint4(p[0], p[1], p[2], p[3]);
    dst[1] = make_uint4(p[4], p[5], p[6], p[7]);
}

// Pass 2: EXACT R6 kernel (best measured config: BM=32, BK=128, one barrier/step,
// A via global_load_lds double-buffer, B direct from L2-resident annP).
__global__ __launch_bounds__(128) void gconv_kernel(const float* __restrict__ A,
                                                    const unsigned short* __restrict__ annP,
                                                    const float* __restrict__ bias,
                                                    float* __restrict__ out) {
    __shared__ alignas(16) char lds[2][16384];  // 32 rows x 128 k fp32, double-buffered

    int bi = blockIdx.x;
    int b = bi & 7;            // batch == XCD -> annP[b] (512 KB) L2-resident per XCD
    int n0 = (bi >> 3) << 5;   // 128 row-tiles per batch
    int t = threadIdx.x, lane = t & 63, wf = t >> 6;  // 2 waves: f-halves
    int r = lane & 31, h = lane >> 5;

    const float* Ab = A + (size_t)b * NN * NN + (size_t)n0 * NN;

    // staging sources: LDS slot byte s = j*2048 + t*16 holds A[row][k0 + q*4 .. +3]
    // row = s>>9 (512 B rows), q = ((s&511) ^ ((row&15)<<4)) >> 4
    const float* asrc[8];
#pragma unroll
    for (int j = 0; j < 8; ++j) {
        unsigned s = (unsigned)(j * 2048 + t * 16);
        unsigned row = s >> 9;
        unsigned q = ((s & 511u) ^ ((row & 15u) << 4)) >> 4;
        asrc[j] = Ab + (size_t)row * NN + q * 4;
    }
    auto STAGE = [&](int buf, int k0) {
        char* base = lds[buf];
#pragma unroll
        for (int j = 0; j < 8; ++j) gload16(asrc[j] + k0, base + j * 2048 + wf * 1024);
    };

    // B fragment base: lane -> (f = wf*32 + r, k-half h); fragment kb at +kb*1024 elems
    const unsigned short* bfp =
        annP + (size_t)b * NKB * 1024 + (size_t)(wf * 32 + r) * 16 + h * 8;

    unsigned rbase = (unsigned)(r * 512);
    unsigned swz = (unsigned)((r & 15) << 4);

    f32x16 acc = {};
    uint4 bfrag[8];

    STAGE(0, 0);
#pragma unroll 1
    for (int s = 0; s < NSTEP; ++s) {
        int cur = s & 1;
        // stage for buf[cur] was issued a full iteration ago -> latency covered
        asm volatile("s_waitcnt vmcnt(0)" ::: "memory");
        __builtin_amdgcn_s_barrier();
        asm volatile("" ::: "memory");

        // B loads FIRST (so their waits never drain the stage issued after them)
        int kb0 = s * 8;
#pragma unroll
        for (int kc = 0; kc < 8; ++kc)
            bfrag[kc] = *(const uint4*)(bfp + (size_t)(kb0 + kc) * 1024);

        if (s + 1 < NSTEP) STAGE(cur ^ 1, (s + 1) * BK);  // into the idle buffer

        const char* bufA = lds[cur];
#pragma unroll
        for (int kc = 0; kc < 8; ++kc) {
            unsigned ao = rbase + (unsigned)(kc * 64 + h * 32);
            float4 a0 = *(const float4*)(bufA + (ao ^ swz));
            float4 a1 = *(const float4*)(bufA + ((ao + 16) ^ swz));
            bf16x8 af = {(__bf16)a0.x, (__bf16)a0.y, (__bf16)a0.z, (__bf16)a0.w,
                         (__bf16)a1.x, (__bf16)a1.y, (__bf16)a1.z, (__bf16)a1.w};
            acc = __builtin_amdgcn_mfma_f32_32x32x16_bf16(
                af, __builtin_bit_cast(bf16x8, bfrag[kc]), acc, 0, 0, 0);
        }
    }

    // epilogue: D col = lane&31 (f), row = (reg&3) + 8*(reg>>2) + 4*(lane>>5)  (verified)
    float bv = bias[wf * 32 + r];
    float* ob = out + ((size_t)(b * NN + n0)) * FF + wf * 32 + r;
#pragma unroll
    for (int e = 0; e < 16; ++e) {
        int rowl = (e & 3) + 8 * (e >> 2) + h * 4;
        ob[(size_t)rowl * FF] = acc[e] + bv;
    }
}

extern "C" void kernel_launch(void* const* d_in, const int* in_sizes, int n_in,
                              void* d_out, int out_size, void* d_ws, size_t ws_size,
                              hipStream_t stream) {
    const float* adj = (const float*)d_in[0];
    const float* ann = (const float*)d_in[1];
    const float* bias = (const float*)d_in[2];
    float* out = (float*)d_out;
    unsigned short* annP = (unsigned short*)d_ws;  // 8*256*64*16*2 = 4 MiB

    annP_kernel<<<dim3(8 * 64), dim3(256), 0, stream>>>(ann, annP);
    // MEASUREMENT ROUND: gconv launched 3x (idempotent — identical output each time).
    // gconv_dur = (total_R9 - total_R6) / 2. Adjacency (512 MB) exceeds L3 (256 MB),
    // so each repetition re-streams from HBM at full cost.
    gconv_kernel<<<dim3(8 * (NN / BM)), dim3(128), 0, stream>>>(adj, annP, bias, out);
    gconv_kernel<<<dim3(8 * (NN / BM)), dim3(128), 0, stream>>>(adj, annP, bias, out);
    gconv_kernel<<<dim3(8 * (NN / BM)), dim3(128), 0, stream>>>(adj, annP, bias, out);
}

// Round 11
// 680.382 us; speedup vs baseline: 1.2931x; 1.2931x over previous
//
#include <hip/hip_runtime.h>
#include <stdint.h>

typedef __bf16 bf16x8 __attribute__((ext_vector_type(8)));
typedef float f32x16 __attribute__((ext_vector_type(16)));

#define NN 4096
#define FF 64
#define BM 32
#define BK 128
#define NSTEP (NN / BK)  // 32
#define NKB (NN / 16)    // 256 k16-blocks

// round-to-nearest-even fp32 -> bf16
__device__ __forceinline__ unsigned short f2bf(float x) {
    unsigned int u = __builtin_bit_cast(unsigned int, x);
    unsigned int r = u + 0x7fffu + ((u >> 16) & 1u);
    return (unsigned short)(r >> 16);
}

__device__ __forceinline__ void gload16(const void* g, void* l) {
    __builtin_amdgcn_global_load_lds((const __attribute__((address_space(1))) void*)g,
                                     (__attribute__((address_space(3))) void*)l, 16, 0, 0);
}

// Pass 1: annP[b][kb][f][kh] = bf16(ann[b][kb*16+kh][f])  — B fragment for k-block kb
// is 16 B/lane, 1 KB contiguous per wave. (Validated R4/R6: absmax 0.5.)
__global__ __launch_bounds__(256) void annP_kernel(const float* __restrict__ ann,
                                                   unsigned short* __restrict__ annP) {
    int blk = blockIdx.x;
    int b = blk >> 6;
    int kb = (blk & 63) * 4 + (threadIdx.x >> 6);
    int f = threadIdx.x & 63;
    const float* src = ann + (size_t)(b * NN + kb * 16) * FF + f;
    unsigned short v[16];
#pragma unroll
    for (int kh = 0; kh < 16; ++kh) v[kh] = f2bf(src[(size_t)kh * FF]);
    unsigned int p[8];
#pragma unroll
    for (int i = 0; i < 8; ++i) p[i] = (unsigned)v[2 * i] | ((unsigned)v[2 * i + 1] << 16);
    uint4* dst = (uint4*)(annP + ((size_t)(b * NKB + kb) * 64 + f) * 16);
    dst[0] = make_uint4(p[0], p[1], p[2], p[3]);
    dst[1] = make_uint4(p[4], p[5], p[6], p[7]);
}

// Pass 2: best measured config (R6; marginal cost measured R9: ~100 µs vs ~84 µs
// streaming floor). BM=32, 128 threads (4 blocks/CU), BK=128, ONE barrier per step.
// A staged via global_load_lds (pre-swizzled source, linear LDS dest, full-iteration
// prefetch distance); B fragments direct from L2-resident annP (batch==XCD swizzle).
__global__ __launch_bounds__(128) void gconv_kernel(const float* __restrict__ A,
                                                    const unsigned short* __restrict__ annP,
                                                    const float* __restrict__ bias,
                                                    float* __restrict__ out) {
    __shared__ alignas(16) char lds[2][16384];  // 32 rows x 128 k fp32, double-buffered

    int bi = blockIdx.x;
    int b = bi & 7;            // batch == XCD -> annP[b] (512 KB) L2-resident per XCD
    int n0 = (bi >> 3) << 5;   // 128 row-tiles per batch
    int t = threadIdx.x, lane = t & 63, wf = t >> 6;  // 2 waves: f-halves
    int r = lane & 31, h = lane >> 5;

    const float* Ab = A + (size_t)b * NN * NN + (size_t)n0 * NN;

    // staging sources: LDS slot byte s = j*2048 + t*16 holds A[row][k0 + q*4 .. +3]
    // row = s>>9 (512 B rows), q = ((s&511) ^ ((row&15)<<4)) >> 4
    const float* asrc[8];
#pragma unroll
    for (int j = 0; j < 8; ++j) {
        unsigned s = (unsigned)(j * 2048 + t * 16);
        unsigned row = s >> 9;
        unsigned q = ((s & 511u) ^ ((row & 15u) << 4)) >> 4;
        asrc[j] = Ab + (size_t)row * NN + q * 4;
    }
    auto STAGE = [&](int buf, int k0) {
        char* base = lds[buf];
#pragma unroll
        for (int j = 0; j < 8; ++j) gload16(asrc[j] + k0, base + j * 2048 + wf * 1024);
    };

    // B fragment base: lane -> (f = wf*32 + r, k-half h); fragment kb at +kb*1024 elems
    const unsigned short* bfp =
        annP + (size_t)b * NKB * 1024 + (size_t)(wf * 32 + r) * 16 + h * 8;

    unsigned rbase = (unsigned)(r * 512);
    unsigned swz = (unsigned)((r & 15) << 4);

    f32x16 acc = {};
    uint4 bfrag[8];

    STAGE(0, 0);
#pragma unroll 1
    for (int s = 0; s < NSTEP; ++s) {
        int cur = s & 1;
        // stage for buf[cur] was issued a full iteration ago -> latency covered
        asm volatile("s_waitcnt vmcnt(0)" ::: "memory");
        __builtin_amdgcn_s_barrier();
        asm volatile("" ::: "memory");

        // B loads FIRST (so their waits never drain the stage issued after them)
        int kb0 = s * 8;
#pragma unroll
        for (int kc = 0; kc < 8; ++kc)
            bfrag[kc] = *(const uint4*)(bfp + (size_t)(kb0 + kc) * 1024);

        if (s + 1 < NSTEP) STAGE(cur ^ 1, (s + 1) * BK);  // into the idle buffer

        const char* bufA = lds[cur];
#pragma unroll
        for (int kc = 0; kc < 8; ++kc) {
            unsigned ao = rbase + (unsigned)(kc * 64 + h * 32);
            float4 a0 = *(const float4*)(bufA + (ao ^ swz));
            float4 a1 = *(const float4*)(bufA + ((ao + 16) ^ swz));
            bf16x8 af = {(__bf16)a0.x, (__bf16)a0.y, (__bf16)a0.z, (__bf16)a0.w,
                         (__bf16)a1.x, (__bf16)a1.y, (__bf16)a1.z, (__bf16)a1.w};
            acc = __builtin_amdgcn_mfma_f32_32x32x16_bf16(
                af, __builtin_bit_cast(bf16x8, bfrag[kc]), acc, 0, 0, 0);
        }
    }

    // epilogue: D col = lane&31 (f), row = (reg&3) + 8*(reg>>2) + 4*(lane>>5)  (verified)
    float bv = bias[wf * 32 + r];
    float* ob = out + ((size_t)(b * NN + n0)) * FF + wf * 32 + r;
#pragma unroll
    for (int e = 0; e < 16; ++e) {
        int rowl = (e & 3) + 8 * (e >> 2) + h * 4;
        ob[(size_t)rowl * FF] = acc[e] + bv;
    }
}

extern "C" void kernel_launch(void* const* d_in, const int* in_sizes, int n_in,
                              void* d_out, int out_size, void* d_ws, size_t ws_size,
                              hipStream_t stream) {
    const float* adj = (const float*)d_in[0];
    const float* ann = (const float*)d_in[1];
    const float* bias = (const float*)d_in[2];
    float* out = (float*)d_out;
    unsigned short* annP = (unsigned short*)d_ws;  // 8*256*64*16*2 = 4 MiB

    annP_kernel<<<dim3(8 * 64), dim3(256), 0, stream>>>(ann, annP);
    gconv_kernel<<<dim3(8 * (NN / BM)), dim3(128), 0, stream>>>(adj, annP, bias, out);
}